// Round 6
// baseline (4112.751 us; speedup 1.0000x reference)
//
#include <hip/hip_runtime.h>
#include <cstdint>
#include <cstddef>

#define B_   64
#define T_   2048
#define C_   64
#define H_   256
#define G3_  768    // 3*H
#define HOR_ 96

typedef _Float16 h2 __attribute__((ext_vector_type(2)));
typedef _Float16 h8 __attribute__((ext_vector_type(8)));

// ---------------------------------------------------------------------------
// K1: cur[b,t,h] = sum_c x[b,t,c]*snn_w[h,c] + snn_b[h]     (fp32)
// ---------------------------------------------------------------------------
#define K1_TT 128
__global__ __launch_bounds__(256) void k_cur(const float* __restrict__ x,
                                             const float* __restrict__ w,
                                             const float* __restrict__ bias,
                                             float* __restrict__ cur) {
  __shared__ float xs[K1_TT * C_];  // 32 KB
  const int b = blockIdx.x;
  const int t0 = blockIdx.y * K1_TT;
  const int tid = threadIdx.x;

  const float4* xsrc = (const float4*)(x + ((size_t)b * T_ + t0) * C_);
  float4* xdst = (float4*)xs;
#pragma unroll
  for (int i = 0; i < (K1_TT * C_ / 4) / 256; i++)
    xdst[tid + i * 256] = xsrc[tid + i * 256];

  float wr[C_];
  const float4* wp = (const float4*)(w + (size_t)tid * C_);
#pragma unroll
  for (int q = 0; q < C_ / 4; q++) {
    float4 v = wp[q];
    wr[4 * q + 0] = v.x; wr[4 * q + 1] = v.y;
    wr[4 * q + 2] = v.z; wr[4 * q + 3] = v.w;
  }
  const float bb = bias[tid];
  __syncthreads();

  for (int t = 0; t < K1_TT; t++) {
    const float4* xrow = (const float4*)(xs + t * C_);
    float a0 = 0.f, a1 = 0.f;
#pragma unroll
    for (int q = 0; q < C_ / 4; q += 2) {
      float4 v0 = xrow[q];
      float4 v1 = xrow[q + 1];
      a0 += wr[4 * q + 0] * v0.x + wr[4 * q + 1] * v0.y +
            wr[4 * q + 2] * v0.z + wr[4 * q + 3] * v0.w;
      a1 += wr[4 * q + 4] * v1.x + wr[4 * q + 5] * v1.y +
            wr[4 * q + 6] * v1.z + wr[4 * q + 7] * v1.w;
    }
    cur[((size_t)b * T_ + t0 + t) * H_ + tid] = a0 + a1 + bb;
  }
}

// ---------------------------------------------------------------------------
// K2: LIF scan per (b,h). Spikes stored as u8 (exact).
// ---------------------------------------------------------------------------
__global__ __launch_bounds__(64) void k_lif(const float* __restrict__ cur,
                                            unsigned char* __restrict__ spk) {
  const int b = blockIdx.x >> 2;
  const int h = ((blockIdx.x & 3) << 6) + threadIdx.x;
  const float* cp = cur + (size_t)b * T_ * H_ + h;
  unsigned char* sp = spk + (size_t)b * T_ * H_ + h;
  float mem = 0.f;
#pragma unroll 8
  for (int t = 0; t < T_; t++) {
    float c = cp[(size_t)t * H_];
    float reset = (mem > 1.0f) ? 1.0f : 0.0f;  // from previous mem
    mem = 0.9f * mem + c - reset;              // THR = 1
    sp[(size_t)t * H_] = (mem > 1.0f) ? (unsigned char)1 : (unsigned char)0;
  }
}

// ---------------------------------------------------------------------------
// K3: gx[m,g] = sum_k hcomb[m,k]*wih[g,k] + bih[g]   -> stored fp16
//     hcomb = [x (k<64) | spk (k>=64)], M=131072, K=320, N=768
// fp32 LDS-tiled GEMM: BM=128 BN=64 BK=32, 256 threads, 4x8 per-thread tile.
// ---------------------------------------------------------------------------
#define BM 128
#define BN 64
#define BK 32
__global__ __launch_bounds__(256) void k_gx(const float* __restrict__ x,
                                            const unsigned char* __restrict__ spk,
                                            const float* __restrict__ wih,
                                            const float* __restrict__ bih,
                                            _Float16* __restrict__ gx) {
  __shared__ float As[BK][BM];  // 16 KB
  __shared__ float Bs[BK][BN];  // 8 KB
  const int nb = blockIdx.x;
  const int mb = blockIdx.y;
  const int m0 = mb * BM, n0 = nb * BN;
  const int tid = threadIdx.x;
  const int tm = (tid & 31) * 4;
  const int tn = (tid >> 5) * 8;

  float acc[4][8] = {};

  for (int k0 = 0; k0 < 320; k0 += BK) {
    if (k0 < 64) {
#pragma unroll
      for (int i = 0; i < 4; i++) {
        int idx = tid + i * 256;
        int r = idx >> 3;
        int c4 = (idx & 7) * 4;
        float4 v = *(const float4*)(x + (size_t)(m0 + r) * C_ + k0 + c4);
        As[c4 + 0][r] = v.x; As[c4 + 1][r] = v.y;
        As[c4 + 2][r] = v.z; As[c4 + 3][r] = v.w;
      }
    } else {
#pragma unroll
      for (int i = 0; i < 4; i++) {
        int idx = tid + i * 256;
        int r = idx >> 3;
        int c4 = (idx & 7) * 4;
        uchar4 u = *(const uchar4*)(spk + (size_t)(m0 + r) * H_ + (k0 - 64) + c4);
        As[c4 + 0][r] = (float)u.x; As[c4 + 1][r] = (float)u.y;
        As[c4 + 2][r] = (float)u.z; As[c4 + 3][r] = (float)u.w;
      }
    }
#pragma unroll
    for (int i = 0; i < 2; i++) {
      int idx = tid + i * 256;
      int r = idx >> 3;
      int c4 = (idx & 7) * 4;
      float4 v = *(const float4*)(wih + (size_t)(n0 + r) * 320 + k0 + c4);
      Bs[c4 + 0][r] = v.x; Bs[c4 + 1][r] = v.y;
      Bs[c4 + 2][r] = v.z; Bs[c4 + 3][r] = v.w;
    }
    __syncthreads();
#pragma unroll
    for (int k = 0; k < BK; k++) {
      float a[4], bv[8];
      *(float4*)&a[0] = *(const float4*)&As[k][tm];
      *(float4*)&bv[0] = *(const float4*)&Bs[k][tn];
      *(float4*)&bv[4] = *(const float4*)&Bs[k][tn + 4];
#pragma unroll
      for (int i = 0; i < 4; i++)
#pragma unroll
        for (int jj = 0; jj < 8; jj++) acc[i][jj] += a[i] * bv[jj];
    }
    __syncthreads();
  }
#pragma unroll
  for (int i = 0; i < 4; i++) {
    size_t m = (size_t)(m0 + tm + i);
    h8 o;
#pragma unroll
    for (int jj = 0; jj < 8; jj++)
      o[jj] = (_Float16)(acc[i][jj] + bih[n0 + tn + jj]);
    *(h8*)(gx + m * G3_ + n0 + tn) = o;
  }
}

// ---------------------------------------------------------------------------
// K4: GRU scan, fdot2, 4-way K split. One block per batch, 1024 threads.
// Thread (j = tid>>2, kq = tid&3): rows {j, j+256, j+512} x K-quarter
// [64kq, 64kq+64) = 96 h2 weight VGPRs. 1024-thread block forces the <=128
// VGPR target, so weights FIT in arch VGPRs (rounds 2/3/5 lesson: >128
// persistent regs always get displaced to AGPRs -> accvgpr_read per fdot2).
// Quad-reduce via shfl_xor(1)+shfl_xor(2); gates redundant x4; ONE
// barrier/step. LDS h padded 64->72 halves/chunk: quad ds_read_b128
// addresses land on disjoint bank quartets (round-5: 6.7e7 conflicts from
// unpadded 256B-apart reads).
// ---------------------------------------------------------------------------
#define HP_ 72   // padded chunk stride (halves)
__global__ __launch_bounds__(1024) void k_gru(const _Float16* __restrict__ gx,
                                              const float* __restrict__ whh,
                                              const float* __restrict__ bhh,
                                              const float* __restrict__ head_w,
                                              const float* __restrict__ head_b,
                                              float* __restrict__ out) {
  const int b = blockIdx.x;
  const int tid = threadIdx.x;
  const int j = tid >> 2;        // 0..255
  const int kq = tid & 3;        // 0..3
  const int k0 = kq * 64;

  alignas(16) __shared__ _Float16 h16[2][4 * HP_];  // 1.1 KB, double-buffered
  __shared__ float hbuf32[H_];                      // 1 KB — final h for head

  // weight slice -> packed half2 registers (96 VGPRs)
  h2 wr[32], wz[32], wn[32];
  {
    const float4* p0 = (const float4*)(whh + (size_t)j * H_ + k0);
    const float4* p1 = (const float4*)(whh + (size_t)(H_ + j) * H_ + k0);
    const float4* p2 = (const float4*)(whh + (size_t)(2 * H_ + j) * H_ + k0);
#pragma unroll
    for (int q = 0; q < 16; q++) {
      float4 a = p0[q];
      wr[2 * q].x = (_Float16)a.x; wr[2 * q].y = (_Float16)a.y;
      wr[2 * q + 1].x = (_Float16)a.z; wr[2 * q + 1].y = (_Float16)a.w;
      float4 c = p1[q];
      wz[2 * q].x = (_Float16)c.x; wz[2 * q].y = (_Float16)c.y;
      wz[2 * q + 1].x = (_Float16)c.z; wz[2 * q + 1].y = (_Float16)c.w;
      float4 d = p2[q];
      wn[2 * q].x = (_Float16)d.x; wn[2 * q].y = (_Float16)d.y;
      wn[2 * q + 1].x = (_Float16)d.z; wn[2 * q + 1].y = (_Float16)d.w;
    }
  }
  const float br_ = bhh[j], bz_ = bhh[H_ + j], bn_ = bhh[2 * H_ + j];

  if (tid < 2 * 4 * HP_) ((_Float16*)h16)[tid] = (_Float16)0.f;
  float hj = 0.f;  // h state for this thread's j (redundant across the quad)
  __syncthreads();

  const _Float16* gxb = gx + (size_t)b * T_ * G3_;
  // prefetch gx for t=0 (quad lanes read same addrs -> same cache line)
  _Float16 pr = gxb[j], pz = gxb[H_ + j], pn = gxb[2 * H_ + j];

  int p = 0;
  for (int t = 0; t < T_; t++) {
    float xr = (float)pr, xz = (float)pz, xn = (float)pn;
    {
      int tn_ = (t + 1 < T_) ? t + 1 : t;
      const _Float16* g = gxb + (size_t)tn_ * G3_;
      pr = g[j]; pz = g[H_ + j]; pn = g[2 * H_ + j];
    }

    // dot phase: 96 fdot2 over this thread's K-quarter
    const _Float16* hb = &h16[p][kq * HP_];
    float ar = 0.f, az = 0.f, an = 0.f;
#pragma unroll
    for (int g2 = 0; g2 < 4; g2++) {
#pragma unroll
      for (int cc = 0; cc < 2; cc++) {
        int c = g2 * 2 + cc;
        h8 hv = *(const h8*)(hb + c * 8);
        const h2* hp = (const h2*)&hv;
#pragma unroll
        for (int i = 0; i < 4; i++) {
          int wi = c * 4 + i;
          ar = __builtin_amdgcn_fdot2(wr[wi], hp[i], ar, false);
          az = __builtin_amdgcn_fdot2(wz[wi], hp[i], az, false);
          an = __builtin_amdgcn_fdot2(wn[wi], hp[i], an, false);
        }
      }
      // pin DS reads to their group (anti-hoist; VALU/SALU/VMEM may cross)
      __builtin_amdgcn_sched_barrier(2 | 4 | 16 | 32 | 64);
    }
    // quad reduction -> all 4 lanes hold full sums
    ar += __shfl_xor(ar, 1, 64); ar += __shfl_xor(ar, 2, 64);
    az += __shfl_xor(az, 1, 64); az += __shfl_xor(az, 2, 64);
    an += __shfl_xor(an, 1, 64); an += __shfl_xor(an, 2, 64);

    // gates (all quad lanes compute identically)
    float r = 1.f / (1.f + __expf(-(xr + ar + br_)));
    float z = 1.f / (1.f + __expf(-(xz + az + bz_)));
    float pre = xn + r * (an + bn_);
    float e = __expf(2.f * pre);          // tanh(x) = 1 - 2/(e^{2x}+1)
    float n = 1.f - 2.f / (e + 1.f);
    hj = (1.f - z) * n + z * hj;

    // write next h buffer (padded layout: h[j] -> chunk j>>6, offset j&63)
    if (kq == 0) h16[p ^ 1][(j >> 6) * HP_ + (j & 63)] = (_Float16)hj;
    p ^= 1;
    __syncthreads();   // the ONLY barrier per step
  }

  if (kq == 0) hbuf32[j] = hj;
  __syncthreads();

  // fused head
  if (tid < HOR_) {
    const float4* hw = (const float4*)(head_w + (size_t)tid * H_);
    const float4* hv4 = (const float4*)hbuf32;
    float acc = head_b[tid];
#pragma unroll
    for (int q = 0; q < H_ / 4; q++) {
      float4 w4 = hw[q];
      float4 v4 = hv4[q];
      acc += w4.x * v4.x + w4.y * v4.y + w4.z * v4.z + w4.w * v4.w;
    }
    out[(size_t)b * HOR_ + tid] = acc;
  }
}

// ---------------------------------------------------------------------------
extern "C" void kernel_launch(void* const* d_in, const int* in_sizes, int n_in,
                              void* d_out, int out_size, void* d_ws, size_t ws_size,
                              hipStream_t stream) {
  const float* x      = (const float*)d_in[0];
  const float* snn_w  = (const float*)d_in[1];
  const float* snn_b  = (const float*)d_in[2];
  const float* wih    = (const float*)d_in[3];
  const float* whh    = (const float*)d_in[4];
  const float* bih    = (const float*)d_in[5];
  const float* bhh    = (const float*)d_in[6];
  const float* head_w = (const float*)d_in[7];
  const float* head_b = (const float*)d_in[8];
  float* out = (float*)d_out;

  // ws layout (235 MB total):
  //   [0, 201326592)          gx fp16 [131072,768]
  //   [0, 134217728)          cur fp32 [131072,256] — alias, dead before k_gx
  //   [201326592, 234881024)  spk u8 [131072,256]
  char* ws = (char*)d_ws;
  _Float16* gx = (_Float16*)ws;
  float* cur = (float*)ws;
  unsigned char* spk = (unsigned char*)(ws + (size_t)201326592);

  k_cur<<<dim3(B_, T_ / K1_TT), 256, 0, stream>>>(x, snn_w, snn_b, cur);
  k_lif<<<dim3(256), 64, 0, stream>>>(cur, spk);
  k_gx<<<dim3(G3_ / BN, (B_ * T_) / BM), 256, 0, stream>>>(x, spk, wih, bih, gx);
  k_gru<<<dim3(B_), 1024, 0, stream>>>(gx, whh, bhh, head_w, head_b, out);
}

// Round 8
// 3596.170 us; speedup vs baseline: 1.1436x; 1.1436x over previous
//
#include <hip/hip_runtime.h>
#include <cstdint>
#include <cstddef>

#define B_   64
#define T_   2048
#define C_   64
#define H_   256
#define G3_  768    // 3*H
#define HOR_ 96

typedef _Float16 h2 __attribute__((ext_vector_type(2)));
typedef _Float16 h8 __attribute__((ext_vector_type(8)));

// ---------------------------------------------------------------------------
// K1: cur[b,t,h] = sum_c x[b,t,c]*snn_w[h,c] + snn_b[h]     (fp32)
// ---------------------------------------------------------------------------
#define K1_TT 128
__global__ __launch_bounds__(256) void k_cur(const float* __restrict__ x,
                                             const float* __restrict__ w,
                                             const float* __restrict__ bias,
                                             float* __restrict__ cur) {
  __shared__ float xs[K1_TT * C_];  // 32 KB
  const int b = blockIdx.x;
  const int t0 = blockIdx.y * K1_TT;
  const int tid = threadIdx.x;

  const float4* xsrc = (const float4*)(x + ((size_t)b * T_ + t0) * C_);
  float4* xdst = (float4*)xs;
#pragma unroll
  for (int i = 0; i < (K1_TT * C_ / 4) / 256; i++)
    xdst[tid + i * 256] = xsrc[tid + i * 256];

  float wr[C_];
  const float4* wp = (const float4*)(w + (size_t)tid * C_);
#pragma unroll
  for (int q = 0; q < C_ / 4; q++) {
    float4 v = wp[q];
    wr[4 * q + 0] = v.x; wr[4 * q + 1] = v.y;
    wr[4 * q + 2] = v.z; wr[4 * q + 3] = v.w;
  }
  const float bb = bias[tid];
  __syncthreads();

  for (int t = 0; t < K1_TT; t++) {
    const float4* xrow = (const float4*)(xs + t * C_);
    float a0 = 0.f, a1 = 0.f;
#pragma unroll
    for (int q = 0; q < C_ / 4; q += 2) {
      float4 v0 = xrow[q];
      float4 v1 = xrow[q + 1];
      a0 += wr[4 * q + 0] * v0.x + wr[4 * q + 1] * v0.y +
            wr[4 * q + 2] * v0.z + wr[4 * q + 3] * v0.w;
      a1 += wr[4 * q + 4] * v1.x + wr[4 * q + 5] * v1.y +
            wr[4 * q + 6] * v1.z + wr[4 * q + 7] * v1.w;
    }
    cur[((size_t)b * T_ + t0 + t) * H_ + tid] = a0 + a1 + bb;
  }
}

// ---------------------------------------------------------------------------
// K2: LIF scan per (b,h). Spikes stored as u8 (exact).
// ---------------------------------------------------------------------------
__global__ __launch_bounds__(64) void k_lif(const float* __restrict__ cur,
                                            unsigned char* __restrict__ spk) {
  const int b = blockIdx.x >> 2;
  const int h = ((blockIdx.x & 3) << 6) + threadIdx.x;
  const float* cp = cur + (size_t)b * T_ * H_ + h;
  unsigned char* sp = spk + (size_t)b * T_ * H_ + h;
  float mem = 0.f;
#pragma unroll 8
  for (int t = 0; t < T_; t++) {
    float c = cp[(size_t)t * H_];
    float reset = (mem > 1.0f) ? 1.0f : 0.0f;  // from previous mem
    mem = 0.9f * mem + c - reset;              // THR = 1
    sp[(size_t)t * H_] = (mem > 1.0f) ? (unsigned char)1 : (unsigned char)0;
  }
}

// ---------------------------------------------------------------------------
// K3: gx[m,g] = sum_k hcomb[m,k]*wih[g,k] + bih[g]   -> stored fp16
//     hcomb = [x (k<64) | spk (k>=64)], M=131072, K=320, N=768
// fp32 LDS-tiled GEMM: BM=128 BN=64 BK=32, 256 threads, 4x8 per-thread tile.
// Round-6 fix: +4 leading-stride padding on As/Bs (128-multiple stride made
// staging-write bank = f(r) only -> 8-way conflicts, 1.65e8 counted).
// ---------------------------------------------------------------------------
#define BM 128
#define BN 64
#define BK 32
#define AP (BM + 4)   // 132 floats = 528 B, 16B-aligned rows, bank-decorrelated
#define BP (BN + 4)   // 68 floats = 272 B
__global__ __launch_bounds__(256) void k_gx(const float* __restrict__ x,
                                            const unsigned char* __restrict__ spk,
                                            const float* __restrict__ wih,
                                            const float* __restrict__ bih,
                                            _Float16* __restrict__ gx) {
  alignas(16) __shared__ float As[BK][AP];  // 16.9 KB
  alignas(16) __shared__ float Bs[BK][BP];  // 8.7 KB
  const int nb = blockIdx.x;
  const int mb = blockIdx.y;
  const int m0 = mb * BM, n0 = nb * BN;
  const int tid = threadIdx.x;
  const int tm = (tid & 31) * 4;
  const int tn = (tid >> 5) * 8;

  float acc[4][8] = {};

  for (int k0 = 0; k0 < 320; k0 += BK) {
    if (k0 < 64) {
#pragma unroll
      for (int i = 0; i < 4; i++) {
        int idx = tid + i * 256;
        int r = idx >> 3;
        int c4 = (idx & 7) * 4;
        float4 v = *(const float4*)(x + (size_t)(m0 + r) * C_ + k0 + c4);
        As[c4 + 0][r] = v.x; As[c4 + 1][r] = v.y;
        As[c4 + 2][r] = v.z; As[c4 + 3][r] = v.w;
      }
    } else {
#pragma unroll
      for (int i = 0; i < 4; i++) {
        int idx = tid + i * 256;
        int r = idx >> 3;
        int c4 = (idx & 7) * 4;
        uchar4 u = *(const uchar4*)(spk + (size_t)(m0 + r) * H_ + (k0 - 64) + c4);
        As[c4 + 0][r] = (float)u.x; As[c4 + 1][r] = (float)u.y;
        As[c4 + 2][r] = (float)u.z; As[c4 + 3][r] = (float)u.w;
      }
    }
#pragma unroll
    for (int i = 0; i < 2; i++) {
      int idx = tid + i * 256;
      int r = idx >> 3;
      int c4 = (idx & 7) * 4;
      float4 v = *(const float4*)(wih + (size_t)(n0 + r) * 320 + k0 + c4);
      Bs[c4 + 0][r] = v.x; Bs[c4 + 1][r] = v.y;
      Bs[c4 + 2][r] = v.z; Bs[c4 + 3][r] = v.w;
    }
    __syncthreads();
#pragma unroll
    for (int k = 0; k < BK; k++) {
      float a[4], bv[8];
      *(float4*)&a[0] = *(const float4*)&As[k][tm];
      *(float4*)&bv[0] = *(const float4*)&Bs[k][tn];
      *(float4*)&bv[4] = *(const float4*)&Bs[k][tn + 4];
#pragma unroll
      for (int i = 0; i < 4; i++)
#pragma unroll
        for (int jj = 0; jj < 8; jj++) acc[i][jj] += a[i] * bv[jj];
    }
    __syncthreads();
  }
#pragma unroll
  for (int i = 0; i < 4; i++) {
    size_t m = (size_t)(m0 + tm + i);
    h8 o;
#pragma unroll
    for (int jj = 0; jj < 8; jj++)
      o[jj] = (_Float16)(acc[i][jj] + bih[n0 + tn + jj]);
    *(h8*)(gx + m * G3_ + n0 + tn) = o;
  }
}

// ---------------------------------------------------------------------------
// K4: GRU scan — one whh ROW per thread. One block per batch, 768 threads
// (12 waves = 3/SIMD). amdgpu_waves_per_eu(3,3) pins the occupancy target so
// the allocator's budget is floor(512/3)=170 regs/thread — the 128 h2 weight
// regs + ~30 temps fit in ARCH VGPRs (rounds 2/3/5/6 lesson: without a
// max-waves clause the compiler shrinks arch to 64-128 for occupancy and
// displaces weights to AGPRs; fdot2 can't read AGPRs -> 2x dot cost).
// Thread g: gh[g] = whh[g,:]·h + bhh[g] (full K, single output, no shfl).
// ROUND-7 BUG FIX: dot loop must cover 32 h8-chunks (32x8 = 256 halves =
// full K); round 7 had 16 -> half the matvec dropped -> absmax 7.7e-2.
// h16 reads are same-address across all lanes -> LDS broadcast, no conflicts.
// 2 barriers/step (dots -> gh publish -> gates -> h16 publish).
// ---------------------------------------------------------------------------
__global__
__attribute__((amdgpu_waves_per_eu(3, 3)))
__launch_bounds__(768)
void k_gru(const _Float16* __restrict__ gx,
           const float* __restrict__ whh,
           const float* __restrict__ bhh,
           const float* __restrict__ head_w,
           const float* __restrict__ head_b,
           float* __restrict__ out) {
  const int b = blockIdx.x;
  const int g = threadIdx.x;     // 0..767: owns gate-row g of whh

  alignas(16) __shared__ _Float16 h16[H_];   // 512 B — current h (fp16)
  __shared__ float gh[G3_];                  // 3 KB  — matvec results
  alignas(4) __shared__ _Float16 gxs[G3_];   // 1.5 KB — gx_t staging
  __shared__ float hbuf32[H_];               // 1 KB  — final h for head

  // weight row g -> 128 packed h2 regs
  h2 w[128];
  {
    const float4* wp = (const float4*)(whh + (size_t)g * H_);
#pragma unroll
    for (int q = 0; q < 64; q++) {
      float4 v = wp[q];
      w[2 * q].x     = (_Float16)v.x; w[2 * q].y     = (_Float16)v.y;
      w[2 * q + 1].x = (_Float16)v.z; w[2 * q + 1].y = (_Float16)v.w;
    }
  }
  const float bg = bhh[g];
  if (g < H_) h16[g] = (_Float16)0.f;
  float hj = 0.f;  // h state (threads g<256 only)
  __syncthreads();

  const _Float16* gxb = gx + (size_t)b * T_ * G3_ + g;
  _Float16 pg = gxb[0];  // prefetch t=0

  for (int t = 0; t < T_; t++) {
    // publish gx_t (read by gates after barrier 1), prefetch t+1
    gxs[g] = pg;
    {
      int tn_ = (t + 1 < T_) ? t + 1 : t;
      pg = gxb[(size_t)tn_ * G3_];
    }

    // dot: gh[g] = w[g,:]·h (+bias). 32 h8-chunks = 256 halves = full K.
    // 4 partial accumulators break the dependency chain.
    float a0 = 0.f, a1 = 0.f, a2 = 0.f, a3 = 0.f;
#pragma unroll
    for (int c = 0; c < 32; c++) {
      h8 hv = *(const h8*)(h16 + c * 8);
      const h2* hp = (const h2*)&hv;
      a0 = __builtin_amdgcn_fdot2(w[4 * c + 0], hp[0], a0, false);
      a1 = __builtin_amdgcn_fdot2(w[4 * c + 1], hp[1], a1, false);
      a2 = __builtin_amdgcn_fdot2(w[4 * c + 2], hp[2], a2, false);
      a3 = __builtin_amdgcn_fdot2(w[4 * c + 3], hp[3], a3, false);
    }
    gh[g] = (a0 + a1) + (a2 + a3) + bg;
    __syncthreads();   // barrier 1: gh + gxs complete

    // gates on threads 0..255 (1 wave/SIMD)
    if (g < H_) {
      float hr = gh[g], hz = gh[H_ + g], hn = gh[2 * H_ + g];
      float xr = (float)gxs[g];
      float xz = (float)gxs[H_ + g];
      float xn = (float)gxs[2 * H_ + g];
      float r = 1.f / (1.f + __expf(-(xr + hr)));
      float z = 1.f / (1.f + __expf(-(xz + hz)));
      float pre = xn + r * hn;
      float e = __expf(2.f * pre);          // tanh(x) = 1 - 2/(e^{2x}+1)
      float n = 1.f - 2.f / (e + 1.f);
      hj = (1.f - z) * n + z * hj;
      h16[g] = (_Float16)hj;
    }
    __syncthreads();   // barrier 2: h16 ready for next step
  }

  if (g < H_) hbuf32[g] = hj;
  __syncthreads();

  // fused head
  if (g < HOR_) {
    const float4* hw = (const float4*)(head_w + (size_t)g * H_);
    const float4* hv4 = (const float4*)hbuf32;
    float acc = head_b[g];
#pragma unroll
    for (int q = 0; q < H_ / 4; q++) {
      float4 w4 = hw[q];
      float4 v4 = hv4[q];
      acc += w4.x * v4.x + w4.y * v4.y + w4.z * v4.z + w4.w * v4.w;
    }
    out[(size_t)b * HOR_ + g] = acc;
  }
}

// ---------------------------------------------------------------------------
extern "C" void kernel_launch(void* const* d_in, const int* in_sizes, int n_in,
                              void* d_out, int out_size, void* d_ws, size_t ws_size,
                              hipStream_t stream) {
  const float* x      = (const float*)d_in[0];
  const float* snn_w  = (const float*)d_in[1];
  const float* snn_b  = (const float*)d_in[2];
  const float* wih    = (const float*)d_in[3];
  const float* whh    = (const float*)d_in[4];
  const float* bih    = (const float*)d_in[5];
  const float* bhh    = (const float*)d_in[6];
  const float* head_w = (const float*)d_in[7];
  const float* head_b = (const float*)d_in[8];
  float* out = (float*)d_out;

  // ws layout (235 MB total):
  //   [0, 201326592)          gx fp16 [131072,768]
  //   [0, 134217728)          cur fp32 [131072,256] — alias, dead before k_gx
  //   [201326592, 234881024)  spk u8 [131072,256]
  char* ws = (char*)d_ws;
  _Float16* gx = (_Float16*)ws;
  float* cur = (float*)ws;
  unsigned char* spk = (unsigned char*)(ws + (size_t)201326592);

  k_cur<<<dim3(B_, T_ / K1_TT), 256, 0, stream>>>(x, snn_w, snn_b, cur);
  k_lif<<<dim3(256), 64, 0, stream>>>(cur, spk);
  k_gx<<<dim3(G3_ / BN, (B_ * T_) / BM), 256, 0, stream>>>(x, spk, wih, bih, gx);
  k_gru<<<dim3(B_), 768, 0, stream>>>(gx, whh, bhh, head_w, head_b, out);
}